// Round 3
// baseline (484.117 us; speedup 1.0000x reference)
//
#include <hip/hip_runtime.h>
#include <hip/hip_bf16.h>
#include <hip/hip_fp16.h>

#define NN   20000
#define EE   320000
#define EN   340000   // EE + NN (self loops)
#define HH   8
#define CC   56
#define HC   448
#define DEA  5
#define EAS  8        // csr_ea stride in uints (dup-packed half2; 32 B lines)
#define DINN 32
#define GG   32
#define NEG  0.2f

#define SS   896      // xl|xr row stride
#define MT   157      // gemm2 M-tiles (ceil(20000/128))
#define NT   7        // gemm2 N-tiles (896/128)

#define ATT_BLOCKS 1024
#define ATT_WAVES  (ATT_BLOCKS * 4)
#define ATT_NB     4   // nodes per batch

typedef short bf16x8 __attribute__((ext_vector_type(8)));
typedef float f32x4  __attribute__((ext_vector_type(4)));
typedef float f32x8  __attribute__((ext_vector_type(8)));

static __device__ __forceinline__ unsigned short f2bf(float f) {
  unsigned int u = __float_as_uint(f);
  u += 0x7fffu + ((u >> 16) & 1u);   // round-to-nearest-even
  return (unsigned short)(u >> 16);
}

static __device__ __forceinline__ __half2 uash2(unsigned int u) {
  union { unsigned int u; __half2 h; } c; c.u = u; return c.h;
}
static __device__ __forceinline__ unsigned int h2asu(__half2 h) {
  union { __half2 h; unsigned int u; } c; c.h = h; return c.u;
}
// |x| on a packed half2 (clear both sign bits)
static __device__ __forceinline__ __half2 habs2_(__half2 x) {
  return uash2(h2asu(x) & 0x7fff7fffu);
}
static __device__ __forceinline__ unsigned int packh2(float a, float b) {
  unsigned short l = __half_as_ushort(__float2half_rn(a));
  unsigned short h = __half_as_ushort(__float2half_rn(b));
  return ((unsigned int)h << 16) | l;
}

// 8-lane butterfly sum via DPP (pure VALU; no LDS-pipe ds_bpermute).
static __device__ __forceinline__ float dpp8_sum(float x) {
  int v = __float_as_int(x);
  x += __int_as_float(__builtin_amdgcn_update_dpp(0, v, 0xB1, 0xF, 0xF, true));
  v = __float_as_int(x);
  x += __int_as_float(__builtin_amdgcn_update_dpp(0, v, 0x4E, 0xF, 0xF, true));
  v = __float_as_int(x);
  x += __int_as_float(__builtin_amdgcn_update_dpp(0, v, 0x141, 0xF, 0xF, true));
  return x;
}

__global__ void k_deg(const int* __restrict__ dst, int* deg) {
  int e = blockIdx.x * 256 + threadIdx.x;
  if (e < EE) atomicAdd(&deg[dst[e]], 1);
}

// exclusive scan of (deg[n]+1) -> offs[0..NN] and cursor[0..NN-1]
__global__ __launch_bounds__(1024) void k_scan(const int* __restrict__ deg, int* offs,
                                               int* cursor) {
  __shared__ int tot[1024];
  int t = threadIdx.x;
  int base = t * 20;
  int loc[20];
  int s = 0;
  #pragma unroll
  for (int i = 0; i < 20; i++) {
    int idx = base + i;
    int v = (idx < NN) ? deg[idx] + 1 : 0;
    loc[i] = s;
    s += v;
  }
  tot[t] = s;
  __syncthreads();
  for (int o = 1; o < 1024; o <<= 1) {
    int v = (t >= o) ? tot[t - o] : 0;
    __syncthreads();
    tot[t] += v;
    __syncthreads();
  }
  int basesum = (t == 0) ? 0 : tot[t - 1];
  #pragma unroll
  for (int i = 0; i < 20; i++) {
    int idx = base + i;
    if (idx < NN) { offs[idx] = basesum + loc[i]; cursor[idx] = basesum + loc[i]; }
  }
  if (t == 1023) offs[NN] = tot[1023];
}

// scatter real edges; attrs stored as duplicated half2 (ready for v_pk_fma_f16)
__global__ void k_scatter(const int* __restrict__ src, const int* __restrict__ dst,
                          const float* __restrict__ ea,
                          int* cursor, int* __restrict__ csr_src,
                          unsigned int* __restrict__ csr_ea) {
  int i = blockIdx.x * 256 + threadIdx.x;
  if (i >= EE) return;
  int d = dst[i], s = src[i];
  float a[DEA];
  #pragma unroll
  for (int j = 0; j < DEA; j++) a[j] = ea[(size_t)i * DEA + j];
  int pos = atomicAdd(&cursor[d], 1);
  csr_src[pos] = s;
  unsigned int pk[DEA];
  #pragma unroll
  for (int j = 0; j < DEA; j++) pk[j] = packh2(a[j], a[j]);
  unsigned int* o = csr_ea + (size_t)pos * EAS;
  *(uint4*)o       = (uint4){pk[0], pk[1], pk[2], pk[3]};
  *(uint4*)(o + 4) = (uint4){pk[4], 0u, 0u, 0u};
}

// fused: self-loop attrs + x->bf16 cast + W1t/W2t transposed bf16 casts
#define XCN (NN * DINN)
#define W1N (SS * DINN)
#define W2N (SS * HC)
__global__ void k_aux(const int* __restrict__ offs,
                      int* __restrict__ csr_src, unsigned int* __restrict__ csr_ea,
                      const float* __restrict__ x, unsigned short* __restrict__ xb,
                      const float* __restrict__ Wl1, const float* __restrict__ Wr1,
                      unsigned short* __restrict__ W1t,
                      const float* __restrict__ Wl2, const float* __restrict__ Wr2,
                      unsigned short* __restrict__ W2t) {
  int i = blockIdx.x * 256 + threadIdx.x;
  if (i < NN) {
    int n = i;
    int e0 = offs[n], e1 = offs[n + 1] - 1;
    float a0 = 0.f, a1 = 0.f, a2 = 0.f, a3 = 0.f, a4 = 0.f;
    for (int e = e0; e < e1; e++) {
      const unsigned int* p = csr_ea + (size_t)e * EAS;
      a0 += __half2float(__ushort_as_half((unsigned short)p[0]));
      a1 += __half2float(__ushort_as_half((unsigned short)p[1]));
      a2 += __half2float(__ushort_as_half((unsigned short)p[2]));
      a3 += __half2float(__ushort_as_half((unsigned short)p[3]));
      a4 += __half2float(__ushort_as_half((unsigned short)p[4]));
    }
    float inv = 1.f / fmaxf((float)(e1 - e0), 1.f);
    csr_src[e1] = n;
    unsigned int* o = csr_ea + (size_t)e1 * EAS;
    *(uint4*)o       = (uint4){packh2(a0 * inv, a0 * inv), packh2(a1 * inv, a1 * inv),
                               packh2(a2 * inv, a2 * inv), packh2(a3 * inv, a3 * inv)};
    *(uint4*)(o + 4) = (uint4){packh2(a4 * inv, a4 * inv), 0u, 0u, 0u};
    return;
  }
  i -= NN;
  if (i < XCN) { xb[i] = f2bf(x[i]); return; }
  i -= XCN;
  if (i < W1N) {
    int col = i / DINN, k = i - col * DINN;
    int cc = (col < HC) ? col : col - HC;
    const float* W = (col < HC) ? Wl1 : Wr1;
    W1t[i] = f2bf(W[(size_t)k * HC + cc]);
    return;
  }
  i -= W1N;
  if (i < W2N) {
    int col = i / HC, k = i - col * HC;
    int cc = (col < HC) ? col : col - HC;
    const float* W = (col < HC) ? Wl2 : Wr2;
    W2t[i] = f2bf(W[(size_t)k * HC + cc]);
  }
}

// MFMA gemm1 (transposed operands). Output now f16 (consumed by k_attn's
// packed-f16 pipeline; f16 has MORE mantissa than the previous bf16).
__global__ __launch_bounds__(256) void k_gemm1(const unsigned short* __restrict__ xb,
                                               const unsigned short* __restrict__ W1t,
                                               unsigned short* __restrict__ out) {
  int w = threadIdx.x >> 6, lane = threadIdx.x & 63;
  int q = lane >> 4, r = lane & 15;
  int m0 = blockIdx.x * 64;                    // out-col base
  int node = blockIdx.y * 64 + w * 16 + r;
  int nc = node < NN ? node : NN - 1;
  bf16x8 b = *(const bf16x8*)(xb + (size_t)nc * DINN + q * 8);
  #pragma unroll
  for (int j = 0; j < 4; j++) {
    bf16x8 a = *(const bf16x8*)(W1t + (size_t)(m0 + j * 16 + r) * DINN + q * 8);
    f32x4 acc = {0.f, 0.f, 0.f, 0.f};
    acc = __builtin_amdgcn_mfma_f32_16x16x32_bf16(a, b, acc, 0, 0, 0);
    uint2 st;
    st.x = packh2(acc[0], acc[1]);
    st.y = packh2(acc[2], acc[3]);
    if (node < NN)
      *(uint2*)(out + (size_t)node * SS + m0 + j * 16 + q * 4) = st;
  }
}

// Fused GATv2 attention, round-3 structure:
//  - persistent waves (1024 blocks x 4 waves, static first 4 nodes + atomic
//    work queue for the tail) -> load balance + layer constants hoisted
//  - packed-f16 score pipeline (v_pk_fma_f16): u = xr + ea.We + xl, then
//    lrelu(u) = 0.6u + 0.4|u|, att-dot in half2, f32 accumulate
//  - 4-edge groups: gathers issued at group top, src indices prefetched one
//    group ahead, edge-attr via scalar s_load (dup-packed half2)
__global__ __launch_bounds__(256) void k_attn(
    const unsigned short* __restrict__ xlr,   // f16 bits
    const int* __restrict__ offs, const int* __restrict__ csr_src,
    const unsigned int* __restrict__ csr_ea,
    const float* __restrict__ We, const float* __restrict__ att,
    const float* __restrict__ bias,
    unsigned short* __restrict__ outb, float* __restrict__ outf,
    int* __restrict__ ctr, int layer1) {
  int lane = threadIdx.x & 63;
  int head = lane >> 3, sub = lane & 7;
  bool v = sub < 7;                        // 7 subs x 8ch = 56 channels/head
  int cb = head * 56 + (v ? sub : 6) * 8;  // clamped channel base (loads safe)

  f32x8 z = {0.f,0.f,0.f,0.f,0.f,0.f,0.f,0.f};
  // layer-uniform constants in half2 (hoisted: loaded once per wave)
  __half2 w0[4], w1[4], w2[4], w3[4], w4[4], at2[4];
  {
    f32x8 a = *(const f32x8*)(att + cb);
    if (!v) a = z;
    f32x8 W0 = *(const f32x8*)(We + 0 * HC + cb);
    f32x8 W1 = *(const f32x8*)(We + 1 * HC + cb);
    f32x8 W2 = *(const f32x8*)(We + 2 * HC + cb);
    f32x8 W3 = *(const f32x8*)(We + 3 * HC + cb);
    f32x8 W4 = *(const f32x8*)(We + 4 * HC + cb);
    #pragma unroll
    for (int p = 0; p < 4; p++) {
      w0[p] = __floats2half2_rn(W0[2*p], W0[2*p+1]);
      w1[p] = __floats2half2_rn(W1[2*p], W1[2*p+1]);
      w2[p] = __floats2half2_rn(W2[2*p], W2[2*p+1]);
      w3[p] = __floats2half2_rn(W3[2*p], W3[2*p+1]);
      w4[p] = __floats2half2_rn(W4[2*p], W4[2*p+1]);
      at2[p] = __floats2half2_rn(a[2*p], a[2*p+1]);
    }
  }
  f32x8 b8 = *(const f32x8*)(bias + cb);
  const __half2 c06 = __float2half2_rn(0.6f);
  const __half2 c04 = __float2half2_rn(0.4f);

  int wid = __builtin_amdgcn_readfirstlane(blockIdx.x * 4 + (threadIdx.x >> 6));
  int nbase = wid * ATT_NB;

  while (nbase < NN) {
    int nend = nbase + ATT_NB; if (nend > NN) nend = NN;
    for (int n = nbase; n < nend; n++) {
      uint4 xru = *(const uint4*)(xlr + (size_t)n * SS + HC + cb);
      __half2 xr2[4] = {uash2(xru.x), uash2(xru.y), uash2(xru.z), uash2(xru.w)};

      int e0 = offs[n], e1 = offs[n + 1], last = e1 - 1;
      float l = 0.f;
      f32x8 acc = z;

      int sA[4];
      #pragma unroll
      for (int k = 0; k < 4; k++) {
        int ek = e0 + k; ek = ek < last ? ek : last;
        sA[k] = csr_src[ek];                 // scalar chain -> s_load
      }

      for (int e = e0; e < e1; e += 4) {
        uint4 g[4];
        #pragma unroll
        for (int k = 0; k < 4; k++)
          g[k] = *(const uint4*)(xlr + (size_t)sA[k] * SS + cb);
        int en = e + 4;
        if (en < e1) {
          #pragma unroll
          for (int k = 0; k < 4; k++) {
            int ek = en + k; ek = ek < last ? ek : last;
            sA[k] = csr_src[ek];
          }
        }
        uint4 mu[4]; unsigned int m4u[4];
        #pragma unroll
        for (int k = 0; k < 4; k++) {
          int ek = e + k; ek = ek < last ? ek : last;
          const unsigned int* p = csr_ea + (size_t)ek * EAS;
          mu[k] = *(const uint4*)p; m4u[k] = p[4];
        }
        #pragma unroll
        for (int k = 0; k < 4; k++) {
          __half2 a0 = uash2(mu[k].x), a1 = uash2(mu[k].y), a2 = uash2(mu[k].z),
                  a3 = uash2(mu[k].w), a4 = uash2(m4u[k]);
          __half2 xl2[4] = {uash2(g[k].x), uash2(g[k].y), uash2(g[k].z), uash2(g[k].w)};
          __half2 pd = uash2(0u);
          #pragma unroll
          for (int p2 = 0; p2 < 4; p2++) {
            __half2 t = __hfma2(a0, w0[p2], xr2[p2]);
            t = __hfma2(a1, w1[p2], t);
            t = __hfma2(a2, w2[p2], t);
            t = __hfma2(a3, w3[p2], t);
            t = __hfma2(a4, w4[p2], t);
            t = __hadd2(t, xl2[p2]);
            t = __hfma2(c04, habs2_(t), __hmul2(c06, t));  // leakyrelu(0.2)
            pd = __hfma2(t, at2[p2], pd);
          }
          float ps = __low2float(pd) + __high2float(pd);
          ps = dpp8_sum(ps);
          float wv = (e + k < e1) ? __expf(fminf(ps, 60.f)) : 0.f;
          #pragma unroll
          for (int p2 = 0; p2 < 4; p2++) {
            float2 f = __half22float2(xl2[p2]);
            acc[2*p2]   += wv * f.x;
            acc[2*p2+1] += wv * f.y;
          }
          l += wv;
        }
      }

      f32x8 o = acc * (1.f / (l + 1e-16f)) + b8;
      if (layer1) {
        if (v) {
          #pragma unroll
          for (int i = 0; i < 8; i++) o[i] = o[i] > 0.f ? o[i] : (__expf(o[i]) - 1.f);
          uint4 pk;
          pk.x = ((unsigned int)f2bf(o[1]) << 16) | f2bf(o[0]);
          pk.y = ((unsigned int)f2bf(o[3]) << 16) | f2bf(o[2]);
          pk.z = ((unsigned int)f2bf(o[5]) << 16) | f2bf(o[4]);
          pk.w = ((unsigned int)f2bf(o[7]) << 16) | f2bf(o[6]);
          *(uint4*)(outb + (size_t)n * HC + cb) = pk;
        }
      } else if (v) {
        float* dst = outf + (size_t)n * HC + cb;
        *(f32x4*)dst       = (f32x4){o[0], o[1], o[2], o[3]};
        *(f32x4*)(dst + 4) = (f32x4){o[4], o[5], o[6], o[7]};
      }
    }
    // grab next batch from the queue (static region covers the first
    // ATT_WAVES*ATT_NB nodes; ~900 atomics total, no startup burst)
    int t;
    if (lane == 0) t = atomicAdd(ctr, 1);
    t = __shfl(t, 0, 64);
    nbase = __builtin_amdgcn_readfirstlane(ATT_WAVES * ATT_NB + t * ATT_NB);
  }
}

// per-channel sum / sumsq over NN rows of bf16 h1
__global__ __launch_bounds__(448) void k_bnstats(const unsigned short* __restrict__ h,
                                                 float* stat) {
  int c = threadIdx.x;
  int rows_per = (NN + gridDim.x - 1) / gridDim.x;
  int r0 = blockIdx.x * rows_per, r1 = min(NN, r0 + rows_per);
  float s = 0.f, sq = 0.f;
  for (int r = r0; r < r1; r++) {
    unsigned int u = h[(size_t)r * HC + c];
    float v = __uint_as_float(u << 16);
    s += v; sq += v * v;
  }
  atomicAdd(&stat[c], s);
  atomicAdd(&stat[HC + c], sq);
}

// fold BN into W2: W2s[j][k] = bf16(sc[k]*W2t[j][k]); bias2[j] = sum_k sh[k]*W2t[j][k]
__global__ __launch_bounds__(64) void k_w2fix(const unsigned short* __restrict__ W2t,
                                              const float* __restrict__ stat,
                                              const float* __restrict__ gam,
                                              const float* __restrict__ bet,
                                              unsigned short* __restrict__ W2s,
                                              float* __restrict__ bias2) {
  int j = blockIdx.x;
  int t = threadIdx.x;
  float bacc = 0.f;
  #pragma unroll
  for (int it = 0; it < 7; it++) {
    int k = t + it * 64;
    float w = __uint_as_float((unsigned int)W2t[(size_t)j * HC + k] << 16);
    float mean = stat[k] * (1.f / NN);
    float var  = stat[HC + k] * (1.f / NN) - mean * mean;
    float sc = rsqrtf(var + 1e-5f) * gam[k];
    float sh = bet[k] - mean * sc;
    bacc += sh * w;
    W2s[(size_t)j * HC + k] = f2bf(sc * w);
  }
  #pragma unroll
  for (int m = 32; m >= 1; m >>= 1) bacc += __shfl_xor(bacc, m, 64);
  if (t == 0) bias2[j] = bacc;
}

// LDS-staged bf16 MFMA GEMM with XOR-swizzled LDS. Output f16 (for k_attn).
__global__ __launch_bounds__(256) void k_gemm2(const unsigned short* __restrict__ A,
                                               const unsigned short* __restrict__ Bt,
                                               const float* __restrict__ bias2,
                                               unsigned short* __restrict__ out) {
  __shared__ unsigned short As[128 * 64];
  __shared__ unsigned short Bs[128 * 64];
  int bid = blockIdx.x;
  int g = bid / 56, rem = bid - g * 56;
  int xs = min(8, MT - g * 8);
  int bx = g * 8 + rem % xs;
  int by = rem / xs;
  int t = threadIdx.x;
  int w = t >> 6, lane = t & 63;
  int wm = w >> 1, wn = w & 1;
  int q = lane >> 4, r = lane & 15;
  int m0 = bx * 128;
  int n0 = by * 128;

  const unsigned short *ag[4], *bg[4];
  unsigned short *la[4], *lb[4];
  #pragma unroll
  for (int j = 0; j < 4; j++) {
    int s = t + j * 256;
    int row = s >> 3;
    int gcol = (s & 7) ^ (row & 7);       // fetch-permute for bank swizzle
    int ar = m0 + row; if (ar >= NN) ar = NN - 1;
    ag[j] = A + (size_t)ar * HC + gcol * 8;
    bg[j] = Bt + (size_t)(n0 + row) * HC + gcol * 8;
    la[j] = As + s * 8;
    lb[j] = Bs + s * 8;
  }

  f32x4 zero = {0.f, 0.f, 0.f, 0.f};
  f32x4 acc[4][4];
  #pragma unroll
  for (int i = 0; i < 4; i++)
    #pragma unroll
    for (int j = 0; j < 4; j++) acc[i][j] = zero;

  for (int k0 = 0; k0 < HC; k0 += 64) {
    #pragma unroll
    for (int j = 0; j < 4; j++) {
      __builtin_amdgcn_global_load_lds(
          (const __attribute__((address_space(1))) unsigned int*)(ag[j] + k0),
          (__attribute__((address_space(3))) unsigned int*)la[j], 16, 0, 0);
      __builtin_amdgcn_global_load_lds(
          (const __attribute__((address_space(1))) unsigned int*)(bg[j] + k0),
          (__attribute__((address_space(3))) unsigned int*)lb[j], 16, 0, 0);
    }
    __syncthreads();
    #pragma unroll
    for (int kk = 0; kk < 64; kk += 32) {
      int p = (kk >> 3) + q;
      bf16x8 af[4], bf[4];
      #pragma unroll
      for (int i = 0; i < 4; i++) {
        int row = wm * 64 + i * 16 + r;
        af[i] = *(const bf16x8*)(As + row * 64 + ((p ^ (r & 7)) * 8));
      }
      #pragma unroll
      for (int j = 0; j < 4; j++) {
        int row = wn * 64 + j * 16 + r;
        bf[j] = *(const bf16x8*)(Bs + row * 64 + ((p ^ (r & 7)) * 8));
      }
      #pragma unroll
      for (int i = 0; i < 4; i++)
        #pragma unroll
        for (int j = 0; j < 4; j++)
          acc[i][j] = __builtin_amdgcn_mfma_f32_16x16x32_bf16(af[i], bf[j], acc[i][j], 0, 0, 0);
    }
    __syncthreads();
  }

  #pragma unroll
  for (int j = 0; j < 4; j++) {
    int col = n0 + wn * 64 + j * 16 + r;
    float bs = bias2[col];
    #pragma unroll
    for (int i = 0; i < 4; i++) {
      int row_base = m0 + wm * 64 + i * 16 + q * 4;
      #pragma unroll
      for (int reg = 0; reg < 4; reg++) {
        int row = row_base + reg;
        if (row < NN)
          out[(size_t)row * SS + col] =
              __half_as_ushort(__float2half_rn(acc[i][j][reg] + bs));
      }
    }
  }
}

// segment-sum pool over sorted batch; also counts rows per graph (thread 0)
__global__ __launch_bounds__(448) void k_pool(const float* __restrict__ h2,
                                              const int* __restrict__ batch,
                                              float* pooled, int* cnt) {
  int c = threadIdx.x;
  int rows_per = (NN + gridDim.x - 1) / gridDim.x;
  int r0 = blockIdx.x * rows_per, r1 = min(NN, r0 + rows_per);
  if (r0 >= r1) return;
  float loc = 0.f;
  int rc = 0;
  int gcur = batch[r0];
  for (int r = r0; r < r1; r++) {
    int g = batch[r];
    if (g != gcur) {
      atomicAdd(&pooled[gcur * HC + c], loc);
      if (c == 0) atomicAdd(&cnt[gcur], rc);
      loc = 0.f; rc = 0; gcur = g;
    }
    loc += h2[(size_t)r * HC + c];
    rc++;
  }
  atomicAdd(&pooled[gcur * HC + c], loc);
  if (c == 0) atomicAdd(&cnt[gcur], rc);
}

// pooled mean -> BN over 32 graphs -> logits -> log_softmax (single block)
__global__ __launch_bounds__(448) void k_final(const float* __restrict__ pooled_sum,
                                               const int* __restrict__ cnt,
                                               const float* __restrict__ gam,
                                               const float* __restrict__ bet,
                                               const float* __restrict__ Wlin,
                                               const float* __restrict__ blin,
                                               float* __restrict__ out) {
  __shared__ float P[GG * HC];
  __shared__ float L[GG * 18];
  __shared__ float red[GG];
  int c = threadIdx.x;
  float s = 0.f, sq = 0.f;
  for (int g = 0; g < GG; g++) {
    float v = pooled_sum[g * HC + c] / fmaxf((float)cnt[g], 1.f);
    P[g * HC + c] = v; s += v; sq += v * v;
  }
  float mean = s * (1.f / GG);
  float var  = sq * (1.f / GG) - mean * mean;
  float sc = rsqrtf(var + 1e-5f) * gam[c];
  float sh = bet[c] - mean * sc;
  for (int g = 0; g < GG; g++) P[g * HC + c] = P[g * HC + c] * sc + sh;
  __syncthreads();
  for (int o = c; o < GG * 18; o += HC) {
    int g = o / 18, j = o - g * 18;
    float acc = blin[j];
    for (int k = 0; k < HC; k++) acc += P[g * HC + k] * Wlin[k * 18 + j];
    L[o] = acc;
  }
  __syncthreads();
  if (c < GG) {
    float mx = -3.4e38f;
    for (int j = 0; j < 18; j++) mx = fmaxf(mx, L[c * 18 + j]);
    float se = 0.f;
    for (int j = 0; j < 18; j++) se += __expf(L[c * 18 + j] - mx);
    red[c] = mx + logf(se);
  }
  __syncthreads();
  for (int o = c; o < GG * 18; o += HC) out[o] = L[o] - red[o / 18];
}

extern "C" void kernel_launch(void* const* d_in, const int* in_sizes, int n_in,
                              void* d_out, int out_size, void* d_ws, size_t ws_size,
                              hipStream_t stream) {
  (void)in_sizes; (void)n_in; (void)out_size; (void)ws_size;
  const float* x     = (const float*)d_in[0];
  const int*   ei    = (const int*)d_in[1];
  const float* ea    = (const float*)d_in[2];
  const int*   batch = (const int*)d_in[3];
  const float* Wl1   = (const float*)d_in[4];
  const float* Wr1   = (const float*)d_in[5];
  const float* We1   = (const float*)d_in[6];
  const float* att1  = (const float*)d_in[7];
  const float* bias1 = (const float*)d_in[8];
  const float* Wl2   = (const float*)d_in[9];
  const float* Wr2   = (const float*)d_in[10];
  const float* We2   = (const float*)d_in[11];
  const float* att2  = (const float*)d_in[12];
  const float* bias2in = (const float*)d_in[13];
  const float* gam   = (const float*)d_in[14];
  const float* bet   = (const float*)d_in[15];
  const float* Wlin  = (const float*)d_in[16];
  const float* blin  = (const float*)d_in[17];
  float* out = (float*)d_out;
  const int* srcp = ei;
  const int* dstp = ei + EE;

  char* ws = (char*)d_ws;
  size_t off = 0;
  auto alloc = [&](size_t bytes) -> char* {
    char* p = ws + off;
    off = (off + bytes + 255) & ~(size_t)255;
    return p;
  };
  // zero-region: deg | bnstat | pooled | cnt | attctr (contiguous, one memset)
  int*   deg     = (int*)  alloc(NN * 4);
  float* bnstat  = (float*)alloc(HC * 2 * 4);
  float* pooled  = (float*)alloc(GG * HC * 4 + GG * 4 + 2 * 4);
  int*   cnt     = (int*)(pooled + GG * HC);
  int*   attctr  = cnt + GG;
  size_t zlen    = (size_t)((char*)(attctr + 2) - (char*)deg);

  int*   offs    = (int*)  alloc((NN + 1) * 4);
  int*   cursor  = (int*)  alloc(NN * 4);
  int*   csr_src = (int*)  alloc((size_t)EN * 4);
  unsigned int* csr_ea = (unsigned int*)alloc((size_t)EN * EAS * 4);
  unsigned short* xlr = (unsigned short*)alloc((size_t)NN * SS * 2); // f16
  unsigned short* h1b = (unsigned short*)alloc((size_t)NN * HC * 2); // L1 out bf16
  float* h1f     = (float*)alloc((size_t)NN * HC * 4);               // L2 out fp32
  unsigned short* xb  = (unsigned short*)alloc((size_t)NN * DINN * 2);
  unsigned short* W1t = (unsigned short*)alloc((size_t)SS * DINN * 2);
  unsigned short* W2t = (unsigned short*)alloc((size_t)SS * HC * 2);
  unsigned short* W2s = (unsigned short*)alloc((size_t)SS * HC * 2);
  float* bias2   = (float*)alloc(SS * 4);

  // ---- preprocessing: CSR by dst ----
  hipMemsetAsync(deg, 0, zlen, stream);
  k_deg<<<(EE + 255) / 256, 256, 0, stream>>>(dstp, deg);
  k_scan<<<1, 1024, 0, stream>>>(deg, offs, cursor);
  k_scatter<<<(EE + 255) / 256, 256, 0, stream>>>(srcp, dstp, ea, cursor, csr_src, csr_ea);
  k_aux<<<(NN + XCN + W1N + W2N + 255) / 256, 256, 0, stream>>>(
      offs, csr_src, csr_ea, x, xb, Wl1, Wr1, W1t, Wl2, Wr2, W2t);

  // ---- layer 1 ----
  dim3 g1(SS / 64, (NN + 63) / 64);
  k_gemm1<<<g1, 256, 0, stream>>>(xb, W1t, xlr);
  k_attn<<<ATT_BLOCKS, 256, 0, stream>>>(xlr, offs, csr_src, csr_ea,
                                         We1, att1, bias1, h1b, h1f, attctr, 1);
  // ---- BN (stats + fold into W2) ----
  k_bnstats<<<512, HC, 0, stream>>>(h1b, bnstat);
  k_w2fix<<<SS, 64, 0, stream>>>(W2t, bnstat, gam, bet, W2s, bias2);

  // ---- layer 2 ----
  k_gemm2<<<MT * NT, 256, 0, stream>>>(h1b, W2s, bias2, xlr);
  k_attn<<<ATT_BLOCKS, 256, 0, stream>>>(xlr, offs, csr_src, csr_ea,
                                         We2, att2, bias2in, h1b, h1f, attctr + 1, 0);

  // ---- pool + final ----
  k_pool<<<640, HC, 0, stream>>>(h1f, batch, pooled, cnt);
  k_final<<<1, HC, 0, stream>>>(pooled, cnt, gam, bet, Wlin, blin, out);
}

// Round 4
// 470.755 us; speedup vs baseline: 1.0284x; 1.0284x over previous
//
#include <hip/hip_runtime.h>
#include <hip/hip_bf16.h>

#define NN   20000
#define EE   320000
#define EN   340000   // EE + NN (self loops)
#define HH   8
#define CC   56
#define HC   448
#define DEA  5
#define EAS  16       // csr_ea stride (floats; DUPLICATED pairs a0a0a1a1..; 64 B)
#define DINN 32
#define GG   32
#define NEG  0.2f

#define SS   896      // xl|xr row stride
#define MT   157      // gemm2 M-tiles (ceil(20000/128))
#define NT   7        // gemm2 N-tiles (896/128)

typedef short bf16x8 __attribute__((ext_vector_type(8)));
typedef float f32x2  __attribute__((ext_vector_type(2)));
typedef float f32x4  __attribute__((ext_vector_type(4)));
typedef float f32x8  __attribute__((ext_vector_type(8)));

static __device__ __forceinline__ unsigned short f2bf(float f) {
  unsigned int u = __float_as_uint(f);
  u += 0x7fffu + ((u >> 16) & 1u);   // round-to-nearest-even
  return (unsigned short)(u >> 16);
}

// packed 2xf32 VALU ops (VOP3P; CDNA2+). Pure data-flow asm: schedulable.
static __device__ __forceinline__ f32x2 pk_fma(f32x2 a, f32x2 b, f32x2 c) {
  f32x2 d;
  asm("v_pk_fma_f32 %0, %1, %2, %3" : "=v"(d) : "v"(a), "v"(b), "v"(c));
  return d;
}
static __device__ __forceinline__ f32x2 pk_add(f32x2 a, f32x2 b) {
  f32x2 d;
  asm("v_pk_add_f32 %0, %1, %2" : "=v"(d) : "v"(a), "v"(b));
  return d;
}
static __device__ __forceinline__ f32x2 pk_mul(f32x2 a, f32x2 b) {
  f32x2 d;
  asm("v_pk_mul_f32 %0, %1, %2" : "=v"(d) : "v"(a), "v"(b));
  return d;
}

// 8-lane butterfly sum via DPP (pure VALU; no LDS-pipe ds_bpermute).
static __device__ __forceinline__ float dpp8_sum(float x) {
  int v = __float_as_int(x);
  x += __int_as_float(__builtin_amdgcn_update_dpp(0, v, 0xB1, 0xF, 0xF, true));
  v = __float_as_int(x);
  x += __int_as_float(__builtin_amdgcn_update_dpp(0, v, 0x4E, 0xF, 0xF, true));
  v = __float_as_int(x);
  x += __int_as_float(__builtin_amdgcn_update_dpp(0, v, 0x141, 0xF, 0xF, true));
  return x;
}

__global__ void k_deg(const int* __restrict__ dst, int* deg) {
  int e = blockIdx.x * 256 + threadIdx.x;
  if (e < EE) atomicAdd(&deg[dst[e]], 1);
}

// exclusive scan of (deg[n]+1) -> offs[0..NN] and cursor[0..NN-1]
__global__ __launch_bounds__(1024) void k_scan(const int* __restrict__ deg, int* offs,
                                               int* cursor) {
  __shared__ int tot[1024];
  int t = threadIdx.x;
  int base = t * 20;
  int loc[20];
  int s = 0;
  #pragma unroll
  for (int i = 0; i < 20; i++) {
    int idx = base + i;
    int v = (idx < NN) ? deg[idx] + 1 : 0;
    loc[i] = s;
    s += v;
  }
  tot[t] = s;
  __syncthreads();
  for (int o = 1; o < 1024; o <<= 1) {
    int v = (t >= o) ? tot[t - o] : 0;
    __syncthreads();
    tot[t] += v;
    __syncthreads();
  }
  int basesum = (t == 0) ? 0 : tot[t - 1];
  #pragma unroll
  for (int i = 0; i < 20; i++) {
    int idx = base + i;
    if (idx < NN) { offs[idx] = basesum + loc[i]; cursor[idx] = basesum + loc[i]; }
  }
  if (t == 1023) offs[NN] = tot[1023];
}

// scatter real edges; attrs stored as DUPLICATED f32 pairs (pk_fma operands)
__global__ void k_scatter(const int* __restrict__ src, const int* __restrict__ dst,
                          const float* __restrict__ ea,
                          int* cursor, int* __restrict__ csr_src, float* __restrict__ csr_ea) {
  int i = blockIdx.x * 256 + threadIdx.x;
  if (i >= EE) return;
  int d = dst[i], s = src[i];
  float a[DEA];
  #pragma unroll
  for (int j = 0; j < DEA; j++) a[j] = ea[(size_t)i * DEA + j];
  int pos = atomicAdd(&cursor[d], 1);
  csr_src[pos] = s;
  float* o = csr_ea + (size_t)pos * EAS;
  *(f32x4*)o       = (f32x4){a[0], a[0], a[1], a[1]};
  *(f32x4*)(o + 4) = (f32x4){a[2], a[2], a[3], a[3]};
  *(f32x4*)(o + 8) = (f32x4){a[4], a[4], 0.f, 0.f};
}

// fused: self-loop attrs + x->bf16 cast + W1t/W2t transposed bf16 casts
#define XCN (NN * DINN)
#define W1N (SS * DINN)
#define W2N (SS * HC)
__global__ void k_aux(const int* __restrict__ offs,
                      int* __restrict__ csr_src, float* __restrict__ csr_ea,
                      const float* __restrict__ x, unsigned short* __restrict__ xb,
                      const float* __restrict__ Wl1, const float* __restrict__ Wr1,
                      unsigned short* __restrict__ W1t,
                      const float* __restrict__ Wl2, const float* __restrict__ Wr2,
                      unsigned short* __restrict__ W2t) {
  int i = blockIdx.x * 256 + threadIdx.x;
  if (i < NN) {
    int n = i;
    int e0 = offs[n], e1 = offs[n + 1] - 1;
    float a0 = 0.f, a1 = 0.f, a2 = 0.f, a3 = 0.f, a4 = 0.f;
    for (int e = e0; e < e1; e++) {
      const float* p = csr_ea + (size_t)e * EAS;
      a0 += p[0]; a1 += p[2]; a2 += p[4]; a3 += p[6]; a4 += p[8];
    }
    float inv = 1.f / fmaxf((float)(e1 - e0), 1.f);
    csr_src[e1] = n;
    float* o = csr_ea + (size_t)e1 * EAS;
    *(f32x4*)o       = (f32x4){a0 * inv, a0 * inv, a1 * inv, a1 * inv};
    *(f32x4*)(o + 4) = (f32x4){a2 * inv, a2 * inv, a3 * inv, a3 * inv};
    *(f32x4*)(o + 8) = (f32x4){a4 * inv, a4 * inv, 0.f, 0.f};
    return;
  }
  i -= NN;
  if (i < XCN) { xb[i] = f2bf(x[i]); return; }
  i -= XCN;
  if (i < W1N) {
    int col = i / DINN, k = i - col * DINN;
    int cc = (col < HC) ? col : col - HC;
    const float* W = (col < HC) ? Wl1 : Wr1;
    W1t[i] = f2bf(W[(size_t)k * HC + cc]);
    return;
  }
  i -= W1N;
  if (i < W2N) {
    int col = i / HC, k = i - col * HC;
    int cc = (col < HC) ? col : col - HC;
    const float* W = (col < HC) ? Wl2 : Wr2;
    W2t[i] = f2bf(W[(size_t)k * HC + cc]);
  }
}

// MFMA gemm1 (transposed operands): A = W1t rows (m = out-col), B = xb rows
// (n = node). bf16 output.
__global__ __launch_bounds__(256) void k_gemm1(const unsigned short* __restrict__ xb,
                                               const unsigned short* __restrict__ W1t,
                                               unsigned short* __restrict__ out) {
  int w = threadIdx.x >> 6, lane = threadIdx.x & 63;
  int q = lane >> 4, r = lane & 15;
  int m0 = blockIdx.x * 64;                    // out-col base
  int node = blockIdx.y * 64 + w * 16 + r;
  int nc = node < NN ? node : NN - 1;
  bf16x8 b = *(const bf16x8*)(xb + (size_t)nc * DINN + q * 8);
  #pragma unroll
  for (int j = 0; j < 4; j++) {
    bf16x8 a = *(const bf16x8*)(W1t + (size_t)(m0 + j * 16 + r) * DINN + q * 8);
    f32x4 acc = {0.f, 0.f, 0.f, 0.f};
    acc = __builtin_amdgcn_mfma_f32_16x16x32_bf16(a, b, acc, 0, 0, 0);
    uint2 st;
    st.x = ((unsigned int)f2bf(acc[1]) << 16) | f2bf(acc[0]);
    st.y = ((unsigned int)f2bf(acc[3]) << 16) | f2bf(acc[2]);
    if (node < NN)
      *(uint2*)(out + (size_t)node * SS + m0 + j * 16 + q * 4) = st;
  }
}

// Fused GATv2 attention — round-1 skeleton (best measured: 1 node/wave,
// 4-edge groups, src prefetch one group ahead via readfirstlane s_load,
// DPP reduce) with the f32 math re-expressed as packed-pair VOP3P ops.
// csr_ea is stored as duplicated pairs so each attr is a ready VGPR pair
// (no broadcast movs); md loads are issued oldest so their vmcnt wait does
// not drain the gathers.
__global__ __launch_bounds__(256) void k_attn(
    const unsigned short* __restrict__ xlr,
    const int* __restrict__ offs, const int* __restrict__ csr_src,
    const float* __restrict__ csr_ea,
    const float* __restrict__ We, const float* __restrict__ att,
    const float* __restrict__ bias,
    unsigned short* __restrict__ outb, float* __restrict__ outf, int layer1) {
  int n = blockIdx.x * 4 + (threadIdx.x >> 6);
  if (n >= NN) return;
  int lane = threadIdx.x & 63;
  int head = lane >> 3, sub = lane & 7;
  bool v = sub < 7;                        // 7 subs x 8ch = 56 channels/head
  int cb = head * 56 + (v ? sub : 6) * 8;  // clamped channel base (loads safe)

  // constants as pairs
  f32x2 xr2[4], at2[4], w0p[4], w1p[4], w2p[4], w3p[4], w4p[4];
  {
    uint4 xru = *(const uint4*)(xlr + (size_t)n * SS + HC + cb);
    unsigned int xw[4] = {xru.x, xru.y, xru.z, xru.w};
    const f32x8 at8 = *(const f32x8*)(att + cb);
    const f32x8 W0 = *(const f32x8*)(We + 0 * HC + cb);
    const f32x8 W1 = *(const f32x8*)(We + 1 * HC + cb);
    const f32x8 W2 = *(const f32x8*)(We + 2 * HC + cb);
    const f32x8 W3 = *(const f32x8*)(We + 3 * HC + cb);
    const f32x8 W4 = *(const f32x8*)(We + 4 * HC + cb);
    #pragma unroll
    for (int p = 0; p < 4; p++) {
      xr2[p] = (f32x2){__uint_as_float(xw[p] << 16),
                       __uint_as_float(xw[p] & 0xffff0000u)};
      at2[p] = v ? (f32x2){at8[2*p], at8[2*p+1]} : (f32x2){0.f, 0.f};
      w0p[p] = (f32x2){W0[2*p], W0[2*p+1]};
      w1p[p] = (f32x2){W1[2*p], W1[2*p+1]};
      w2p[p] = (f32x2){W2[2*p], W2[2*p+1]};
      w3p[p] = (f32x2){W3[2*p], W3[2*p+1]};
      w4p[p] = (f32x2){W4[2*p], W4[2*p+1]};
    }
  }

  int e0 = offs[n], e1 = offs[n + 1];
  int last = e1 - 1;
  float l = 0.f;
  f32x2 accp[4] = {{0.f,0.f},{0.f,0.f},{0.f,0.f},{0.f,0.f}};

  // prologue: src indices for the first edge group (scalar loads)
  int sA[4];
  #pragma unroll
  for (int k = 0; k < 4; k++) {
    int ek = e0 + k; ek = ek < last ? ek : last;
    sA[k] = csr_src[__builtin_amdgcn_readfirstlane(ek)];
  }

  for (int e = e0; e < e1; e += 4) {
    // edge-attr pairs first (oldest in vmcnt queue: waiting on these does
    // not wait on the gathers issued below)
    f32x4 mab[4], mcd[4];
    f32x2 me[4];
    #pragma unroll
    for (int k = 0; k < 4; k++) {
      int ek = e + k; ek = ek < last ? ek : last;
      const float* p = csr_ea + (size_t)ek * EAS;
      mab[k] = *(const f32x4*)p;
      mcd[k] = *(const f32x4*)(p + 4);
      me[k]  = *(const f32x2*)(p + 8);
    }
    // gathers (addresses prefetched last iteration)
    uint4 g[4];
    #pragma unroll
    for (int k = 0; k < 4; k++)
      g[k] = *(const uint4*)(xlr + (size_t)sA[k] * SS + cb);
    // prefetch next group's src indices (scalar pipe, independent)
    int en = e + 4;
    if (en < e1) {
      #pragma unroll
      for (int k = 0; k < 4; k++) {
        int ek = en + k; ek = ek < last ? ek : last;
        sA[k] = csr_src[__builtin_amdgcn_readfirstlane(ek)];
      }
    }

    #pragma unroll
    for (int k = 0; k < 4; k++) {
      f32x2 m0 = (f32x2){mab[k][0], mab[k][1]};
      f32x2 m1 = (f32x2){mab[k][2], mab[k][3]};
      f32x2 m2 = (f32x2){mcd[k][0], mcd[k][1]};
      f32x2 m3 = (f32x2){mcd[k][2], mcd[k][3]};
      f32x2 m4 = me[k];
      unsigned int gw[4] = {g[k].x, g[k].y, g[k].z, g[k].w};
      f32x2 xlp[4];
      #pragma unroll
      for (int p2 = 0; p2 < 4; p2++)
        xlp[p2] = (f32x2){__uint_as_float(gw[p2] << 16),
                          __uint_as_float(gw[p2] & 0xffff0000u)};
      f32x2 pd = (f32x2){0.f, 0.f};
      #pragma unroll
      for (int p2 = 0; p2 < 4; p2++) {
        f32x2 t = pk_fma(m0, w0p[p2], xr2[p2]);
        t = pk_fma(m1, w1p[p2], t);
        t = pk_fma(m2, w2p[p2], t);
        t = pk_fma(m3, w3p[p2], t);
        t = pk_fma(m4, w4p[p2], t);
        t = pk_add(t, xlp[p2]);
        t[0] = fmaxf(t[0], NEG * t[0]);
        t[1] = fmaxf(t[1], NEG * t[1]);
        pd = pk_fma(t, at2[p2], pd);
      }
      float ps = pd[0] + pd[1];
      ps = dpp8_sum(ps);
      float wv = (e + k < e1) ? __expf(fminf(ps, 60.f)) : 0.f;
      f32x2 wv2 = (f32x2){wv, wv};
      #pragma unroll
      for (int p2 = 0; p2 < 4; p2++)
        accp[p2] = pk_fma(wv2, xlp[p2], accp[p2]);
      l += wv;
    }
  }

  f32x8 b8 = *(const f32x8*)(bias + cb);
  float inv = 1.f / (l + 1e-16f);
  f32x8 o;
  #pragma unroll
  for (int p2 = 0; p2 < 4; p2++) {
    o[2*p2]   = accp[p2][0] * inv + b8[2*p2];
    o[2*p2+1] = accp[p2][1] * inv + b8[2*p2+1];
  }
  if (layer1) {
    if (v) {
      #pragma unroll
      for (int i = 0; i < 8; i++) o[i] = o[i] > 0.f ? o[i] : (__expf(o[i]) - 1.f);
      uint4 pk;
      pk.x = ((unsigned int)f2bf(o[1]) << 16) | f2bf(o[0]);
      pk.y = ((unsigned int)f2bf(o[3]) << 16) | f2bf(o[2]);
      pk.z = ((unsigned int)f2bf(o[5]) << 16) | f2bf(o[4]);
      pk.w = ((unsigned int)f2bf(o[7]) << 16) | f2bf(o[6]);
      *(uint4*)(outb + (size_t)n * HC + cb) = pk;
    }
  } else if (v) {
    float* dst = outf + (size_t)n * HC + cb;
    *(f32x4*)dst       = (f32x4){o[0], o[1], o[2], o[3]};
    *(f32x4*)(dst + 4) = (f32x4){o[4], o[5], o[6], o[7]};
  }
}

// per-channel sum / sumsq over NN rows of bf16 h1
__global__ __launch_bounds__(448) void k_bnstats(const unsigned short* __restrict__ h,
                                                 float* stat) {
  int c = threadIdx.x;
  int rows_per = (NN + gridDim.x - 1) / gridDim.x;
  int r0 = blockIdx.x * rows_per, r1 = min(NN, r0 + rows_per);
  float s = 0.f, sq = 0.f;
  for (int r = r0; r < r1; r++) {
    unsigned int u = h[(size_t)r * HC + c];
    float v = __uint_as_float(u << 16);
    s += v; sq += v * v;
  }
  atomicAdd(&stat[c], s);
  atomicAdd(&stat[HC + c], sq);
}

// fold BN into W2: W2s[j][k] = bf16(sc[k]*W2t[j][k]); bias2[j] = sum_k sh[k]*W2t[j][k]
__global__ __launch_bounds__(64) void k_w2fix(const unsigned short* __restrict__ W2t,
                                              const float* __restrict__ stat,
                                              const float* __restrict__ gam,
                                              const float* __restrict__ bet,
                                              unsigned short* __restrict__ W2s,
                                              float* __restrict__ bias2) {
  int j = blockIdx.x;
  int t = threadIdx.x;
  float bacc = 0.f;
  #pragma unroll
  for (int it = 0; it < 7; it++) {
    int k = t + it * 64;
    float w = __uint_as_float((unsigned int)W2t[(size_t)j * HC + k] << 16);
    float mean = stat[k] * (1.f / NN);
    float var  = stat[HC + k] * (1.f / NN) - mean * mean;
    float sc = rsqrtf(var + 1e-5f) * gam[k];
    float sh = bet[k] - mean * sc;
    bacc += sh * w;
    W2s[(size_t)j * HC + k] = f2bf(sc * w);
  }
  #pragma unroll
  for (int m = 32; m >= 1; m >>= 1) bacc += __shfl_xor(bacc, m, 64);
  if (t == 0) bias2[j] = bacc;
}

// LDS-staged bf16 MFMA GEMM with XOR-swizzled LDS. xlr2 = h1b @ W2s^T + bias2.
__global__ __launch_bounds__(256) void k_gemm2(const unsigned short* __restrict__ A,
                                               const unsigned short* __restrict__ Bt,
                                               const float* __restrict__ bias2,
                                               unsigned short* __restrict__ out) {
  __shared__ unsigned short As[128 * 64];
  __shared__ unsigned short Bs[128 * 64];
  int bid = blockIdx.x;
  int g = bid / 56, rem = bid - g * 56;
  int xs = min(8, MT - g * 8);
  int bx = g * 8 + rem % xs;
  int by = rem / xs;
  int t = threadIdx.x;
  int w = t >> 6, lane = t & 63;
  int wm = w >> 1, wn = w & 1;
  int q = lane >> 4, r = lane & 15;
  int m0 = bx * 128;
  int n0 = by * 128;

  const unsigned short *ag[4], *bg[4];
  unsigned short *la[4], *lb[4];
  #pragma unroll
  for (int j = 0; j < 4; j++) {
    int s = t + j * 256;
    int row = s >> 3;
    int gcol = (s & 7) ^ (row & 7);       // fetch-permute for bank swizzle
    int ar = m0 + row; if (ar >= NN) ar = NN - 1;
    ag[j] = A + (size_t)ar * HC + gcol * 8;
    bg[j] = Bt + (size_t)(n0 + row) * HC + gcol * 8;
    la[j] = As + s * 8;
    lb[j] = Bs + s * 8;
  }

  f32x4 zero = {0.f, 0.f, 0.f, 0.f};
  f32x4 acc[4][4];
  #pragma unroll
  for (int i = 0; i < 4; i++)
    #pragma unroll
    for (int j = 0; j < 4; j++) acc[i][j] = zero;

  for (int k0 = 0; k0 < HC; k0 += 64) {
    #pragma unroll
    for (int j = 0; j < 4; j++) {
      __builtin_amdgcn_global_load_lds(
          (const __attribute__((address_space(1))) unsigned int*)(ag[j] + k0),
          (__attribute__((address_space(3))) unsigned int*)la[j], 16, 0, 0);
      __builtin_amdgcn_global_load_lds(
          (const __attribute__((address_space(1))) unsigned int*)(bg[j] + k0),
          (__attribute__((address_space(3))) unsigned int*)lb[j], 16, 0, 0);
    }
    __syncthreads();
    #pragma unroll
    for (int kk = 0; kk < 64; kk += 32) {
      int p = (kk >> 3) + q;
      bf16x8 af[4], bf[4];
      #pragma unroll
      for (int i = 0; i < 4; i++) {
        int row = wm * 64 + i * 16 + r;
        af[i] = *(const bf16x8*)(As + row * 64 + ((p ^ (r & 7)) * 8));
      }
      #pragma unroll
      for (int j = 0; j < 4; j++) {
        int row = wn * 64 + j * 16 + r;
        bf[j] = *(const bf16x8*)(Bs + row * 64 + ((p ^ (r & 7)) * 8));
      }
      #pragma unroll
      for (int i = 0; i < 4; i++)
        #pragma unroll
        for (int j = 0; j < 4; j++)
          acc[i][j] = __builtin_amdgcn_mfma_f32_16x16x32_bf16(af[i], bf[j], acc[i][j], 0, 0, 0);
    }
    __syncthreads();
  }

  #pragma unroll
  for (int j = 0; j < 4; j++) {
    int col = n0 + wn * 64 + j * 16 + r;
    float bs = bias2[col];
    #pragma unroll
    for (int i = 0; i < 4; i++) {
      int row_base = m0 + wm * 64 + i * 16 + q * 4;
      #pragma unroll
      for (int reg = 0; reg < 4; reg++) {
        int row = row_base + reg;
        if (row < NN) out[(size_t)row * SS + col] = f2bf(acc[i][j][reg] + bs);
      }
    }
  }
}

// segment-sum pool over sorted batch; also counts rows per graph (thread 0)
__global__ __launch_bounds__(448) void k_pool(const float* __restrict__ h2,
                                              const int* __restrict__ batch,
                                              float* pooled, int* cnt) {
  int c = threadIdx.x;
  int rows_per = (NN + gridDim.x - 1) / gridDim.x;
  int r0 = blockIdx.x * rows_per, r1 = min(NN, r0 + rows_per);
  if (r0 >= r1) return;
  float loc = 0.f;
  int rc = 0;
  int gcur = batch[r0];
  for (int r = r0; r < r1; r++) {
    int g = batch[r];
    if (g != gcur) {
      atomicAdd(&pooled[gcur * HC + c], loc);
      if (c == 0) atomicAdd(&cnt[gcur], rc);
      loc = 0.f; rc = 0; gcur = g;
    }
    loc += h2[(size_t)r * HC + c];
    rc++;
  }
  atomicAdd(&pooled[gcur * HC + c], loc);
  if (c == 0) atomicAdd(&cnt[gcur], rc);
}

// pooled mean -> BN over 32 graphs -> logits -> log_softmax (single block)
__global__ __launch_bounds__(448) void k_final(const float* __restrict__ pooled_sum,
                                               const int* __restrict__ cnt,
                                               const float* __restrict__ gam,
                                               const float* __restrict__ bet,
                                               const float* __restrict__ Wlin,
                                               const float* __restrict__ blin,
                                               float* __restrict__ out) {
  __shared__ float P[GG * HC];
  __shared__ float L[GG * 18];
  __shared__ float red[GG];
  int c = threadIdx.x;
  float s = 0.f, sq = 0.f;
  for (int g = 0; g < GG; g++) {
    float v = pooled_sum[g * HC + c] / fmaxf((float)cnt[g], 1.f);
    P[g * HC + c] = v; s += v; sq += v * v;
  }
  float mean = s * (1.f / GG);
  float var  = sq * (1.f / GG) - mean * mean;
  float sc = rsqrtf(var + 1e-5f) * gam[c];
  float sh = bet[c] - mean * sc;
  for (int g = 0; g < GG; g++) P[g * HC + c] = P[g * HC + c] * sc + sh;
  __syncthreads();
  for (int o = c; o < GG * 18; o += HC) {
    int g = o / 18, j = o - g * 18;
    float acc = blin[j];
    for (int k = 0; k < HC; k++) acc += P[g * HC + k] * Wlin[k * 18 + j];
    L[o] = acc;
  }
  __syncthreads();
  if (c < GG) {
    float mx = -3.4e38f;
    for (int j = 0; j < 18; j++) mx = fmaxf(mx, L[c * 18 + j]);
    float se = 0.f;
    for (int j = 0; j < 18; j++) se += __expf(L[c * 18 + j] - mx);
    red[c] = mx + logf(se);
  }
  __syncthreads();
  for (int o = c; o < GG * 18; o += HC) out[o] = L[o] - red[o / 18];
}

extern "C" void kernel_launch(void* const* d_in, const int* in_sizes, int n_in,
                              void* d_out, int out_size, void* d_ws, size_t ws_size,
                              hipStream_t stream) {
  (void)in_sizes; (void)n_in; (void)out_size; (void)ws_size;
  const float* x     = (const float*)d_in[0];
  const int*   ei    = (const int*)d_in[1];
  const float* ea    = (const float*)d_in[2];
  const int*   batch = (const int*)d_in[3];
  const float* Wl1   = (const float*)d_in[4];
  const float* Wr1   = (const float*)d_in[5];
  const float* We1   = (const float*)d_in[6];
  const float* att1  = (const float*)d_in[7];
  const float* bias1 = (const float*)d_in[8];
  const float* Wl2   = (const float*)d_in[9];
  const float* Wr2   = (const float*)d_in[10];
  const float* We2   = (const float*)d_in[11];
  const float* att2  = (const float*)d_in[12];
  const float* bias2in = (const float*)d_in[13];
  const float* gam   = (const float*)d_in[14];
  const float* bet   = (const float*)d_in[15];
  const float* Wlin  = (const float*)d_in[16];
  const float* blin  = (const float*)d_in[17];
  float* out = (float*)d_out;
  const int* srcp = ei;
  const int* dstp = ei + EE;

  char* ws = (char*)d_ws;
  size_t off = 0;
  auto alloc = [&](size_t bytes) -> char* {
    char* p = ws + off;
    off = (off + bytes + 255) & ~(size_t)255;
    return p;
  };
  // zero-region: deg | bnstat | pooled | cnt (contiguous, one memset)
  int*   deg     = (int*)  alloc(NN * 4);
  float* bnstat  = (float*)alloc(HC * 2 * 4);
  float* pooled  = (float*)alloc(GG * HC * 4 + GG * 4);
  int*   cnt     = (int*)(pooled + GG * HC);
  size_t zlen    = (size_t)((char*)(cnt + GG) - (char*)deg);

  int*   offs    = (int*)  alloc((NN + 1) * 4);
  int*   cursor  = (int*)  alloc(NN * 4);
  int*   csr_src = (int*)  alloc((size_t)EN * 4);
  float* csr_ea  = (float*)alloc((size_t)EN * EAS * 4);
  unsigned short* xlr = (unsigned short*)alloc((size_t)NN * SS * 2); // bf16
  unsigned short* h1b = (unsigned short*)alloc((size_t)NN * HC * 2); // L1 out bf16
  float* h1f     = (float*)alloc((size_t)NN * HC * 4);               // L2 out fp32
  unsigned short* xb  = (unsigned short*)alloc((size_t)NN * DINN * 2);
  unsigned short* W1t = (unsigned short*)alloc((size_t)SS * DINN * 2);
  unsigned short* W2t = (unsigned short*)alloc((size_t)SS * HC * 2);
  unsigned short* W2s = (unsigned short*)alloc((size_t)SS * HC * 2);
  float* bias2   = (float*)alloc(SS * 4);

  // ---- preprocessing: CSR by dst ----
  hipMemsetAsync(deg, 0, zlen, stream);
  k_deg<<<(EE + 255) / 256, 256, 0, stream>>>(dstp, deg);
  k_scan<<<1, 1024, 0, stream>>>(deg, offs, cursor);
  k_scatter<<<(EE + 255) / 256, 256, 0, stream>>>(srcp, dstp, ea, cursor, csr_src, csr_ea);
  k_aux<<<(NN + XCN + W1N + W2N + 255) / 256, 256, 0, stream>>>(
      offs, csr_src, csr_ea, x, xb, Wl1, Wr1, W1t, Wl2, Wr2, W2t);

  // ---- layer 1 ----
  dim3 g1(SS / 64, (NN + 63) / 64);
  k_gemm1<<<g1, 256, 0, stream>>>(xb, W1t, xlr);
  k_attn<<<(NN + 3) / 4, 256, 0, stream>>>(xlr, offs, csr_src, csr_ea,
                                           We1, att1, bias1, h1b, h1f, 1);
  // ---- BN (stats + fold into W2) ----
  k_bnstats<<<512, HC, 0, stream>>>(h1b, bnstat);
  k_w2fix<<<SS, 64, 0, stream>>>(W2t, bnstat, gam, bet, W2s, bias2);

  // ---- layer 2 ----
  k_gemm2<<<MT * NT, 256, 0, stream>>>(h1b, W2s, bias2, xlr);
  k_attn<<<(NN + 3) / 4, 256, 0, stream>>>(xlr, offs, csr_src, csr_ea,
                                           We2, att2, bias2in, h1b, h1f, 0);

  // ---- pool + final ----
  k_pool<<<640, HC, 0, stream>>>(h1f, batch, pooled, cnt);
  k_final<<<1, HC, 0, stream>>>(pooled, cnt, gam, bet, Wlin, blin, out);
}

// Round 5
// 429.304 us; speedup vs baseline: 1.1277x; 1.0966x over previous
//
#include <hip/hip_runtime.h>
#include <hip/hip_bf16.h>

#define NN   20000
#define EE   320000
#define EN   340000   // EE + NN (self loops)
#define HH   8
#define CC   56
#define HC   448
#define DEA  5
#define EAS  8        // padded csr_ea stride (floats; 32 B lines)
#define DINN 32
#define GG   32
#define NEG  0.2f

#define SS   896      // xl|xr row stride
#define MT   157      // gemm2 M-tiles (ceil(20000/128))
#define NT   7        // gemm2 N-tiles (896/128)

typedef short bf16x8 __attribute__((ext_vector_type(8)));
typedef float f32x4  __attribute__((ext_vector_type(4)));
typedef float f32x8  __attribute__((ext_vector_type(8)));

static __device__ __forceinline__ unsigned short f2bf(float f) {
  unsigned int u = __float_as_uint(f);
  u += 0x7fffu + ((u >> 16) & 1u);   // round-to-nearest-even
  return (unsigned short)(u >> 16);
}

static __device__ __forceinline__ f32x8 bf8_to_f32x8(uint4 u) {
  f32x8 o;
  o[0] = __uint_as_float(u.x << 16); o[1] = __uint_as_float(u.x & 0xffff0000u);
  o[2] = __uint_as_float(u.y << 16); o[3] = __uint_as_float(u.y & 0xffff0000u);
  o[4] = __uint_as_float(u.z << 16); o[5] = __uint_as_float(u.z & 0xffff0000u);
  o[6] = __uint_as_float(u.w << 16); o[7] = __uint_as_float(u.w & 0xffff0000u);
  return o;
}

// 8-lane butterfly sum via DPP (pure VALU; no LDS-pipe ds_bpermute).
static __device__ __forceinline__ float dpp8_sum(float x) {
  int v = __float_as_int(x);
  x += __int_as_float(__builtin_amdgcn_update_dpp(0, v, 0xB1, 0xF, 0xF, true));
  v = __float_as_int(x);
  x += __int_as_float(__builtin_amdgcn_update_dpp(0, v, 0x4E, 0xF, 0xF, true));
  v = __float_as_int(x);
  x += __int_as_float(__builtin_amdgcn_update_dpp(0, v, 0x141, 0xF, 0xF, true));
  return x;
}

__global__ void k_deg(const int* __restrict__ dst, int* deg) {
  int e = blockIdx.x * 256 + threadIdx.x;
  if (e < EE) atomicAdd(&deg[dst[e]], 1);
}

// exclusive scan of (deg[n]+1) -> offs[0..NN] and cursor[0..NN-1]
__global__ __launch_bounds__(1024) void k_scan(const int* __restrict__ deg, int* offs,
                                               int* cursor) {
  __shared__ int tot[1024];
  int t = threadIdx.x;
  int base = t * 20;
  int loc[20];
  int s = 0;
  #pragma unroll
  for (int i = 0; i < 20; i++) {
    int idx = base + i;
    int v = (idx < NN) ? deg[idx] + 1 : 0;
    loc[i] = s;
    s += v;
  }
  tot[t] = s;
  __syncthreads();
  for (int o = 1; o < 1024; o <<= 1) {
    int v = (t >= o) ? tot[t - o] : 0;
    __syncthreads();
    tot[t] += v;
    __syncthreads();
  }
  int basesum = (t == 0) ? 0 : tot[t - 1];
  #pragma unroll
  for (int i = 0; i < 20; i++) {
    int idx = base + i;
    if (idx < NN) { offs[idx] = basesum + loc[i]; cursor[idx] = basesum + loc[i]; }
  }
  if (t == 1023) offs[NN] = tot[1023];
}

// scatter real edges; slots [offs[n], offs[n+1]-1); full-32B line writes
__global__ void k_scatter(const int* __restrict__ src, const int* __restrict__ dst,
                          const float* __restrict__ ea,
                          int* cursor, int* __restrict__ csr_src, float* __restrict__ csr_ea) {
  int i = blockIdx.x * 256 + threadIdx.x;
  if (i >= EE) return;
  int d = dst[i], s = src[i];
  float a[DEA];
  #pragma unroll
  for (int j = 0; j < DEA; j++) a[j] = ea[(size_t)i * DEA + j];
  int pos = atomicAdd(&cursor[d], 1);
  csr_src[pos] = s;
  float* o = csr_ea + (size_t)pos * EAS;
  *(f32x4*)o       = (f32x4){a[0], a[1], a[2], a[3]};
  *(f32x4*)(o + 4) = (f32x4){a[4], 0.f, 0.f, 0.f};
}

// fused: self-loop attrs + x->bf16 cast + W1t/W2t transposed bf16 casts
#define XCN (NN * DINN)
#define W1N (SS * DINN)
#define W2N (SS * HC)
__global__ void k_aux(const int* __restrict__ offs,
                      int* __restrict__ csr_src, float* __restrict__ csr_ea,
                      const float* __restrict__ x, unsigned short* __restrict__ xb,
                      const float* __restrict__ Wl1, const float* __restrict__ Wr1,
                      unsigned short* __restrict__ W1t,
                      const float* __restrict__ Wl2, const float* __restrict__ Wr2,
                      unsigned short* __restrict__ W2t) {
  int i = blockIdx.x * 256 + threadIdx.x;
  if (i < NN) {
    int n = i;
    int e0 = offs[n], e1 = offs[n + 1] - 1;
    float a0 = 0.f, a1 = 0.f, a2 = 0.f, a3 = 0.f, a4 = 0.f;
    for (int e = e0; e < e1; e++) {
      const float* p = csr_ea + (size_t)e * EAS;
      a0 += p[0]; a1 += p[1]; a2 += p[2]; a3 += p[3]; a4 += p[4];
    }
    float inv = 1.f / fmaxf((float)(e1 - e0), 1.f);
    csr_src[e1] = n;
    float* o = csr_ea + (size_t)e1 * EAS;
    *(f32x4*)o       = (f32x4){a0 * inv, a1 * inv, a2 * inv, a3 * inv};
    *(f32x4*)(o + 4) = (f32x4){a4 * inv, 0.f, 0.f, 0.f};
    return;
  }
  i -= NN;
  if (i < XCN) { xb[i] = f2bf(x[i]); return; }
  i -= XCN;
  if (i < W1N) {
    int col = i / DINN, k = i - col * DINN;
    int cc = (col < HC) ? col : col - HC;
    const float* W = (col < HC) ? Wl1 : Wr1;
    W1t[i] = f2bf(W[(size_t)k * HC + cc]);
    return;
  }
  i -= W1N;
  if (i < W2N) {
    int col = i / HC, k = i - col * HC;
    int cc = (col < HC) ? col : col - HC;
    const float* W = (col < HC) ? Wl2 : Wr2;
    W2t[i] = f2bf(W[(size_t)k * HC + cc]);
  }
}

// MFMA gemm1 (transposed operands): A = W1t rows (m = out-col), B = xb rows
// (n = node). D: row=q*4+reg -> out-col (4 consecutive per lane -> one 8B
// store), col=r -> node. B-frag shared across the 4 m-tiles.
__global__ __launch_bounds__(256) void k_gemm1(const unsigned short* __restrict__ xb,
                                               const unsigned short* __restrict__ W1t,
                                               unsigned short* __restrict__ out) {
  int w = threadIdx.x >> 6, lane = threadIdx.x & 63;
  int q = lane >> 4, r = lane & 15;
  int m0 = blockIdx.x * 64;                    // out-col base
  int node = blockIdx.y * 64 + w * 16 + r;
  int nc = node < NN ? node : NN - 1;
  bf16x8 b = *(const bf16x8*)(xb + (size_t)nc * DINN + q * 8);
  #pragma unroll
  for (int j = 0; j < 4; j++) {
    bf16x8 a = *(const bf16x8*)(W1t + (size_t)(m0 + j * 16 + r) * DINN + q * 8);
    f32x4 acc = {0.f, 0.f, 0.f, 0.f};
    acc = __builtin_amdgcn_mfma_f32_16x16x32_bf16(a, b, acc, 0, 0, 0);
    uint2 st;
    st.x = ((unsigned int)f2bf(acc[1]) << 16) | f2bf(acc[0]);
    st.y = ((unsigned int)f2bf(acc[3]) << 16) | f2bf(acc[2]);
    if (node < NN)
      *(uint2*)(out + (size_t)node * SS + m0 + j * 16 + q * 4) = st;
  }
}

// Fused GATv2 attention — round-1 proven structure (best measured: 74.4us):
// 1 node/wave, 4-edge groups, src prefetch one group ahead, scalar-pipe edge
// metadata via readfirstlane -> s_load, DPP butterfly reduce.
__global__ __launch_bounds__(256) void k_attn(
    const unsigned short* __restrict__ xlr,
    const int* __restrict__ offs, const int* __restrict__ csr_src,
    const float* __restrict__ csr_ea,
    const float* __restrict__ We, const float* __restrict__ att,
    const float* __restrict__ bias,
    unsigned short* __restrict__ outb, float* __restrict__ outf, int layer1) {
  int n = __builtin_amdgcn_readfirstlane(blockIdx.x * 4 + (threadIdx.x >> 6));
  if (n >= NN) return;
  int lane = threadIdx.x & 63;
  int head = lane >> 3, sub = lane & 7;
  bool v = sub < 7;                        // 7 subs x 8ch = 56 channels/head
  int cb = head * 56 + (v ? sub : 6) * 8;  // clamped channel base (loads safe)

  f32x8 z = {0.f,0.f,0.f,0.f,0.f,0.f,0.f,0.f};
  f32x8 xr = bf8_to_f32x8(*(const uint4*)(xlr + (size_t)n * SS + HC + cb));
  f32x8 at = *(const f32x8*)(att + cb);
  if (!v) at = z;
  f32x8 w0 = *(const f32x8*)(We + 0 * HC + cb);
  f32x8 w1 = *(const f32x8*)(We + 1 * HC + cb);
  f32x8 w2 = *(const f32x8*)(We + 2 * HC + cb);
  f32x8 w3 = *(const f32x8*)(We + 3 * HC + cb);
  f32x8 w4 = *(const f32x8*)(We + 4 * HC + cb);

  int e0 = offs[n], e1 = offs[n + 1];
  int last = e1 - 1;
  float l = 0.f;
  f32x8 acc = z;

  // prologue: src indices for the first edge group (scalar loads)
  int sA[4];
  #pragma unroll
  for (int k = 0; k < 4; k++) {
    int ek = e0 + k; ek = ek < last ? ek : last;
    sA[k] = csr_src[__builtin_amdgcn_readfirstlane(ek)];
  }

  for (int e = e0; e < e1; e += 4) {
    // issue the 4 gathers immediately (addresses prefetched last iteration)
    uint4 g[4];
    #pragma unroll
    for (int k = 0; k < 4; k++)
      g[k] = *(const uint4*)(xlr + (size_t)sA[k] * SS + cb);
    int en = e + 4;
    if (en < e1) {
      #pragma unroll
      for (int k = 0; k < 4; k++) {
        int ek = en + k; ek = ek < last ? ek : last;
        sA[k] = csr_src[__builtin_amdgcn_readfirstlane(ek)];
      }
    }
    f32x8 md[4];
    #pragma unroll
    for (int k = 0; k < 4; k++) {
      int ek = e + k; ek = ek < last ? ek : last;
      md[k] = *(const f32x8*)(csr_ea + (size_t)__builtin_amdgcn_readfirstlane(ek) * EAS);
    }

    #pragma unroll
    for (int k = 0; k < 4; k++) {
      f32x8 tb = xr;
      tb += md[k][0] * w0; tb += md[k][1] * w1; tb += md[k][2] * w2;
      tb += md[k][3] * w3; tb += md[k][4] * w4;
      f32x8 xl = bf8_to_f32x8(g[k]);
      f32x8 t = tb + xl;
      #pragma unroll
      for (int i = 0; i < 8; i++) t[i] = fmaxf(t[i], NEG * t[i]);
      float p = 0.f;
      #pragma unroll
      for (int i = 0; i < 8; i++) p += t[i] * at[i];
      p = dpp8_sum(p);
      float wv = (e + k < e1) ? __expf(fminf(p, 60.f)) : 0.f;
      acc += wv * xl;
      l += wv;
    }
  }

  f32x8 b8 = *(const f32x8*)(bias + cb);
  f32x8 o = acc * (1.f / (l + 1e-16f)) + b8;
  if (layer1) {
    if (v) {
      #pragma unroll
      for (int i = 0; i < 8; i++) o[i] = o[i] > 0.f ? o[i] : (__expf(o[i]) - 1.f);
      uint4 pk;
      pk.x = ((unsigned int)f2bf(o[1]) << 16) | f2bf(o[0]);
      pk.y = ((unsigned int)f2bf(o[3]) << 16) | f2bf(o[2]);
      pk.z = ((unsigned int)f2bf(o[5]) << 16) | f2bf(o[4]);
      pk.w = ((unsigned int)f2bf(o[7]) << 16) | f2bf(o[6]);
      *(uint4*)(outb + (size_t)n * HC + cb) = pk;
    }
  } else if (v) {
    float* dst = outf + (size_t)n * HC + cb;
    *(f32x4*)dst       = (f32x4){o[0], o[1], o[2], o[3]};
    *(f32x4*)(dst + 4) = (f32x4){o[4], o[5], o[6], o[7]};
  }
}

// per-channel sum / sumsq over NN rows of bf16 h1
__global__ __launch_bounds__(448) void k_bnstats(const unsigned short* __restrict__ h,
                                                 float* stat) {
  int c = threadIdx.x;
  int rows_per = (NN + gridDim.x - 1) / gridDim.x;
  int r0 = blockIdx.x * rows_per, r1 = min(NN, r0 + rows_per);
  float s = 0.f, sq = 0.f;
  for (int r = r0; r < r1; r++) {
    unsigned int u = h[(size_t)r * HC + c];
    float v = __uint_as_float(u << 16);
    s += v; sq += v * v;
  }
  atomicAdd(&stat[c], s);
  atomicAdd(&stat[HC + c], sq);
}

// fold BN into W2: W2s[j][k] = bf16(sc[k]*W2t[j][k]); bias2[j] = sum_k sh[k]*W2t[j][k]
__global__ __launch_bounds__(64) void k_w2fix(const unsigned short* __restrict__ W2t,
                                              const float* __restrict__ stat,
                                              const float* __restrict__ gam,
                                              const float* __restrict__ bet,
                                              unsigned short* __restrict__ W2s,
                                              float* __restrict__ bias2) {
  int j = blockIdx.x;
  int t = threadIdx.x;
  float bacc = 0.f;
  #pragma unroll
  for (int it = 0; it < 7; it++) {
    int k = t + it * 64;
    float w = __uint_as_float((unsigned int)W2t[(size_t)j * HC + k] << 16);
    float mean = stat[k] * (1.f / NN);
    float var  = stat[HC + k] * (1.f / NN) - mean * mean;
    float sc = rsqrtf(var + 1e-5f) * gam[k];
    float sh = bet[k] - mean * sc;
    bacc += sh * w;
    W2s[(size_t)j * HC + k] = f2bf(sc * w);
  }
  #pragma unroll
  for (int m = 32; m >= 1; m >>= 1) bacc += __shfl_xor(bacc, m, 64);
  if (t == 0) bias2[j] = bacc;
}

// LDS MFMA GEMM, round-5: DOUBLE-BUFFERED staging with counted vmcnt.
// K-step t+1's global_load_lds are issued before computing step t from the
// other buffer; s_waitcnt vmcnt(8) (not 0) + raw s_barrier lets the next
// tile's 8 loads stay in flight across the barrier (T3/T4 minimum-2-phase).
__global__ __launch_bounds__(256) void k_gemm2(const unsigned short* __restrict__ A,
                                               const unsigned short* __restrict__ Bt,
                                               const float* __restrict__ bias2,
                                               unsigned short* __restrict__ out) {
  __shared__ unsigned short As[2 * 128 * 64];
  __shared__ unsigned short Bs[2 * 128 * 64];
  int bid = blockIdx.x;
  int g = bid / 56, rem = bid - g * 56;
  int xs = min(8, MT - g * 8);
  int bx = g * 8 + rem % xs;
  int by = rem / xs;
  int t = threadIdx.x;
  int w = t >> 6, lane = t & 63;
  int wm = w >> 1, wn = w & 1;
  int q = lane >> 4, r = lane & 15;
  int m0 = bx * 128;
  int n0 = by * 128;

  const unsigned short *ag[4], *bg[4];
  unsigned short *la[4], *lb[4];
  #pragma unroll
  for (int j = 0; j < 4; j++) {
    int s = t + j * 256;
    int row = s >> 3;
    int gcol = (s & 7) ^ (row & 7);       // fetch-permute for bank swizzle
    int ar = m0 + row; if (ar >= NN) ar = NN - 1;
    ag[j] = A + (size_t)ar * HC + gcol * 8;
    bg[j] = Bt + (size_t)(n0 + row) * HC + gcol * 8;
    la[j] = As + s * 8;
    lb[j] = Bs + s * 8;
  }

  f32x4 zero = {0.f, 0.f, 0.f, 0.f};
  f32x4 acc[4][4];
  #pragma unroll
  for (int i = 0; i < 4; i++)
    #pragma unroll
    for (int j = 0; j < 4; j++) acc[i][j] = zero;

#define G2_STAGE(buf, k0)                                                     \
  _Pragma("unroll")                                                           \
  for (int j = 0; j < 4; j++) {                                               \
    __builtin_amdgcn_global_load_lds(                                         \
        (const __attribute__((address_space(1))) unsigned int*)(ag[j] + (k0)),\
        (__attribute__((address_space(3))) unsigned int*)(la[j] + (buf) * (128 * 64)), \
        16, 0, 0);                                                            \
    __builtin_amdgcn_global_load_lds(                                         \
        (const __attribute__((address_space(1))) unsigned int*)(bg[j] + (k0)),\
        (__attribute__((address_space(3))) unsigned int*)(lb[j] + (buf) * (128 * 64)), \
        16, 0, 0);                                                            \
  }

  G2_STAGE(0, 0);
  for (int st = 0; st < NT; ++st) {   // NT==7 K-steps of 64
    int cur = st & 1;
    if (st < NT - 1) {
      G2_STAGE(cur ^ 1, (st + 1) * 64);
      asm volatile("s_waitcnt vmcnt(8)" ::: "memory");   // prev 8 landed
    } else {
      asm volatile("s_waitcnt vmcnt(0)" ::: "memory");
    }
    __builtin_amdgcn_s_barrier();
    const unsigned short* Asc = As + cur * (128 * 64);
    const unsigned short* Bsc = Bs + cur * (128 * 64);
    #pragma unroll
    for (int kk = 0; kk < 64; kk += 32) {
      int p = (kk >> 3) + q;
      bf16x8 af[4], bf[4];
      #pragma unroll
      for (int i = 0; i < 4; i++) {
        int row = wm * 64 + i * 16 + r;
        af[i] = *(const bf16x8*)(Asc + row * 64 + ((p ^ (r & 7)) * 8));
      }
      #pragma unroll
      for (int j = 0; j < 4; j++) {
        int row = wn * 64 + j * 16 + r;
        bf[j] = *(const bf16x8*)(Bsc + row * 64 + ((p ^ (r & 7)) * 8));
      }
      #pragma unroll
      for (int i = 0; i < 4; i++)
        #pragma unroll
        for (int j = 0; j < 4; j++)
          acc[i][j] = __builtin_amdgcn_mfma_f32_16x16x32_bf16(af[i], bf[j], acc[i][j], 0, 0, 0);
    }
    __builtin_amdgcn_s_barrier();   // buf cur free for restage next iter
  }
#undef G2_STAGE

  #pragma unroll
  for (int j = 0; j < 4; j++) {
    int col = n0 + wn * 64 + j * 16 + r;
    float bs = bias2[col];
    #pragma unroll
    for (int i = 0; i < 4; i++) {
      int row_base = m0 + wm * 64 + i * 16 + q * 4;
      #pragma unroll
      for (int reg = 0; reg < 4; reg++) {
        int row = row_base + reg;
        if (row < NN) out[(size_t)row * SS + col] = f2bf(acc[i][j][reg] + bs);
      }
    }
  }
}

// segment-sum pool over sorted batch; also counts rows per graph (thread 0)
__global__ __launch_bounds__(448) void k_pool(const float* __restrict__ h2,
                                              const int* __restrict__ batch,
                                              float* pooled, int* cnt) {
  int c = threadIdx.x;
  int rows_per = (NN + gridDim.x - 1) / gridDim.x;
  int r0 = blockIdx.x * rows_per, r1 = min(NN, r0 + rows_per);
  if (r0 >= r1) return;
  float loc = 0.f;
  int rc = 0;
  int gcur = batch[r0];
  for (int r = r0; r < r1; r++) {
    int g = batch[r];
    if (g != gcur) {
      atomicAdd(&pooled[gcur * HC + c], loc);
      if (c == 0) atomicAdd(&cnt[gcur], rc);
      loc = 0.f; rc = 0; gcur = g;
    }
    loc += h2[(size_t)r * HC + c];
    rc++;
  }
  atomicAdd(&pooled[gcur * HC + c], loc);
  if (c == 0) atomicAdd(&cnt[gcur], rc);
}

// pooled mean -> BN over 32 graphs -> logits -> log_softmax (single block)
__global__ __launch_bounds__(448) void k_final(const float* __restrict__ pooled_sum,
                                               const int* __restrict__ cnt,
                                               const float* __restrict__ gam,
                                               const float* __restrict__ bet,
                                               const float* __restrict__ Wlin,
                                               const float* __restrict__ blin,
                                               float* __restrict__ out) {
  __shared__ float P[GG * HC];
  __shared__ float L[GG * 18];
  __shared__ float red[GG];
  int c = threadIdx.x;
  float s = 0.f, sq = 0.f;
  for (int g = 0; g < GG; g++) {
    float v = pooled_sum[g * HC + c] / fmaxf((float)cnt[g], 1.f);
    P[g * HC + c] = v; s += v; sq += v * v;
  }
  float mean = s * (1.f / GG);
  float var  = sq * (1.f / GG) - mean * mean;
  float sc = rsqrtf(var + 1e-5f) * gam[c];
  float sh = bet[c] - mean * sc;
  for (int g = 0; g < GG; g++) P[g * HC + c] = P[g * HC + c] * sc + sh;
  __syncthreads();
  for (int o = c; o < GG * 18; o += HC) {
    int g = o / 18, j = o - g * 18;
    float acc = blin[j];
    for (int k = 0; k < HC; k++) acc += P[g * HC + k] * Wlin[k * 18 + j];
    L[o] = acc;
  }
  __syncthreads();
  if (c < GG) {
    float mx = -3.4e38f;
    for (int j = 0; j < 18; j++) mx = fmaxf(mx, L[c * 18 + j]);
    float se = 0.f;
    for (int j = 0; j < 18; j++) se += __expf(L[c * 18 + j] - mx);
    red[c] = mx + logf(se);
  }
  __syncthreads();
  for (int o = c; o < GG * 18; o += HC) out[o] = L[o] - red[o / 18];
}

extern "C" void kernel_launch(void* const* d_in, const int* in_sizes, int n_in,
                              void* d_out, int out_size, void* d_ws, size_t ws_size,
                              hipStream_t stream) {
  (void)in_sizes; (void)n_in; (void)out_size; (void)ws_size;
  const float* x     = (const float*)d_in[0];
  const int*   ei    = (const int*)d_in[1];
  const float* ea    = (const float*)d_in[2];
  const int*   batch = (const int*)d_in[3];
  const float* Wl1   = (const float*)d_in[4];
  const float* Wr1   = (const float*)d_in[5];
  const float* We1   = (const float*)d_in[6];
  const float* att1  = (const float*)d_in[7];
  const float* bias1 = (const float*)d_in[8];
  const float* Wl2   = (const float*)d_in[9];
  const float* Wr2   = (const float*)d_in[10];
  const float* We2   = (const float*)d_in[11];
  const float* att2  = (const float*)d_in[12];
  const float* bias2in = (const float*)d_in[13];
  const float* gam   = (const float*)d_in[14];
  const float* bet   = (const float*)d_in[15];
  const float* Wlin  = (const float*)d_in[16];
  const float* blin  = (const float*)d_in[17];
  float* out = (float*)d_out;
  const int* srcp = ei;
  const int* dstp = ei + EE;

  char* ws = (char*)d_ws;
  size_t off = 0;
  auto alloc = [&](size_t bytes) -> char* {
    char* p = ws + off;
    off = (off + bytes + 255) & ~(size_t)255;
    return p;
  };
  // zero-region: deg | bnstat | pooled | cnt (contiguous, one memset)
  int*   deg     = (int*)  alloc(NN * 4);
  float* bnstat  = (float*)alloc(HC * 2 * 4);
  float* pooled  = (float*)alloc(GG * HC * 4 + GG * 4);
  int*   cnt     = (int*)(pooled + GG * HC);
  size_t zlen    = (size_t)((char*)(cnt + GG) - (char*)deg);

  int*   offs    = (int*)  alloc((NN + 1) * 4);
  int*   cursor  = (int*)  alloc(NN * 4);
  int*   csr_src = (int*)  alloc((size_t)EN * 4);
  float* csr_ea  = (float*)alloc((size_t)EN * EAS * 4);
  unsigned short* xlr = (unsigned short*)alloc((size_t)NN * SS * 2); // bf16
  unsigned short* h1b = (unsigned short*)alloc((size_t)NN * HC * 2); // L1 out bf16
  float* h1f     = (float*)alloc((size_t)NN * HC * 4);               // L2 out fp32
  unsigned short* xb  = (unsigned short*)alloc((size_t)NN * DINN * 2);
  unsigned short* W1t = (unsigned short*)alloc((size_t)SS * DINN * 2);
  unsigned short* W2t = (unsigned short*)alloc((size_t)SS * HC * 2);
  unsigned short* W2s = (unsigned short*)alloc((size_t)SS * HC * 2);
  float* bias2   = (float*)alloc(SS * 4);

  // ---- preprocessing: CSR by dst ----
  hipMemsetAsync(deg, 0, zlen, stream);
  k_deg<<<(EE + 255) / 256, 256, 0, stream>>>(dstp, deg);
  k_scan<<<1, 1024, 0, stream>>>(deg, offs, cursor);
  k_scatter<<<(EE + 255) / 256, 256, 0, stream>>>(srcp, dstp, ea, cursor, csr_src, csr_ea);
  k_aux<<<(NN + XCN + W1N + W2N + 255) / 256, 256, 0, stream>>>(
      offs, csr_src, csr_ea, x, xb, Wl1, Wr1, W1t, Wl2, Wr2, W2t);

  // ---- layer 1 ----
  dim3 g1(SS / 64, (NN + 63) / 64);
  k_gemm1<<<g1, 256, 0, stream>>>(xb, W1t, xlr);
  k_attn<<<(NN + 3) / 4, 256, 0, stream>>>(xlr, offs, csr_src, csr_ea,
                                           We1, att1, bias1, h1b, h1f, 1);
  // ---- BN (stats + fold into W2) ----
  k_bnstats<<<512, HC, 0, stream>>>(h1b, bnstat);
  k_w2fix<<<SS, 64, 0, stream>>>(W2t, bnstat, gam, bet, W2s, bias2);

  // ---- layer 2 ----
  k_gemm2<<<MT * NT, 256, 0, stream>>>(h1b, W2s, bias2, xlr);
  k_attn<<<(NN + 3) / 4, 256, 0, stream>>>(xlr, offs, csr_src, csr_ea,
                                           We2, att2, bias2in, h1b, h1f, 0);

  // ---- pool + final ----
  k_pool<<<640, HC, 0, stream>>>(h1f, batch, pooled, cnt);
  k_final<<<1, HC, 0, stream>>>(pooled, cnt, gam, bet, Wlin, blin, out);
}